// Round 12
// baseline (789.540 us; speedup 1.0000x reference)
//
#include <hip/hip_runtime.h>

// ---------------------------------------------------------------------------
// out[b,t,f] = sum_d x[b,t,d] * (W[d,f] / scale[f])
// GEMM: M=8192 (B*T), K=4096 (D), N=16384 (F)
// Round 12: mid-tile barrier reorder. Same data paths as R11 (A via LDS +
// granule swizzle, B fragment-direct from global frag-linear layout, i8
// 16x16x64, 256x128 block, 64x64 wave, 2 blocks/CU, XCD supertile), but the
// last 8 MFMA now execute AFTER the barrier so they cover the a-prefetch
// LDS drain (the 768-cyc/CU hole present in R9-R11) and the next GLL/b
// issues. One barrier/tile. Queue invariant at top: [b01(t),GLLA(t+1),b23(t)].
// ws: [0,32M) xq int8 ; [32M,96M) WTf int8 ; [96M,+32K) xs f32.
// ---------------------------------------------------------------------------

namespace {

constexpr int MD = 8192;    // B*T
constexpr int ND = 16384;   // F
constexpr int KD = 4096;    // D
constexpr int NT = KD / 64; // 64 k-tiles of BK=64

typedef float fl4 __attribute__((ext_vector_type(4)));
typedef unsigned int u32x4 __attribute__((ext_vector_type(4)));
typedef int i32x4 __attribute__((ext_vector_type(4)));

__device__ __forceinline__ unsigned int pack4(fl4 v, float sc) {
  int q0 = __float2int_rn(v.x * sc);
  int q1 = __float2int_rn(v.y * sc);
  int q2 = __float2int_rn(v.z * sc);
  int q3 = __float2int_rn(v.w * sc);
  return (q0 & 0xFF) | ((q1 & 0xFF) << 8) | ((q2 & 0xFF) << 16) |
         ((q3 & 0xFF) << 24);
}

// ---- x fp32 [M][K] -> int8 [M][K] + per-row scale -------------------------
__global__ __launch_bounds__(256) void quant_x_kernel(
    const float* __restrict__ x, signed char* __restrict__ xq,
    float* __restrict__ xs) {
  const int row = blockIdx.x;
  const int t   = threadIdx.x;
  const float* xr = x + (size_t)row * KD + t * 16;
  fl4 v0 = *(const fl4*)(xr);
  fl4 v1 = *(const fl4*)(xr + 4);
  fl4 v2 = *(const fl4*)(xr + 8);
  fl4 v3 = *(const fl4*)(xr + 12);
  float m = 0.f;
  m = fmaxf(m, fmaxf(fmaxf(fabsf(v0.x), fabsf(v0.y)), fmaxf(fabsf(v0.z), fabsf(v0.w))));
  m = fmaxf(m, fmaxf(fmaxf(fabsf(v1.x), fabsf(v1.y)), fmaxf(fabsf(v1.z), fabsf(v1.w))));
  m = fmaxf(m, fmaxf(fmaxf(fabsf(v2.x), fabsf(v2.y)), fmaxf(fabsf(v2.z), fabsf(v2.w))));
  m = fmaxf(m, fmaxf(fmaxf(fabsf(v3.x), fabsf(v3.y)), fmaxf(fabsf(v3.z), fabsf(v3.w))));
#pragma unroll
  for (int off = 32; off; off >>= 1) m = fmaxf(m, __shfl_xor(m, off));
  __shared__ float red[4];
  if ((t & 63) == 0) red[t >> 6] = m;
  __syncthreads();
  m = fmaxf(fmaxf(red[0], red[1]), fmaxf(red[2], red[3]));
  const float sc = (m > 0.f) ? 127.0f / m : 0.f;
  if (t == 0) xs[row] = (m > 0.f) ? m / 127.0f : 0.f;
  u32x4 o;
  o.x = pack4(v0, sc);
  o.y = pack4(v1, sc);
  o.z = pack4(v2, sc);
  o.w = pack4(v3, sc);
  *(u32x4*)(xq + (size_t)row * KD + t * 16) = o;
}

// ---- W int32 [K][N] -> int8 fragment-linear [N/16][K/16][c16][k16] --------
__global__ __launch_bounds__(256) void transpose_w_kernel(
    const int* __restrict__ W, signed char* __restrict__ WTf) {
  constexpr int KC = 64;
  const int nb = blockIdx.x & 63;
  const int kb = blockIdx.x >> 6;
  const int n  = nb * 256 + threadIdx.x;
  const int k0 = kb * KC;
  const int* src = W + (size_t)k0 * ND + n;
  unsigned int buf[16];
#pragma unroll
  for (int i = 0; i < KC; i += 4) {
    unsigned int b0 = (unsigned)src[(size_t)(i + 0) * ND] & 0xFF;
    unsigned int b1 = (unsigned)src[(size_t)(i + 1) * ND] & 0xFF;
    unsigned int b2 = (unsigned)src[(size_t)(i + 2) * ND] & 0xFF;
    unsigned int b3 = (unsigned)src[(size_t)(i + 3) * ND] & 0xFF;
    buf[i >> 2] = b0 | (b1 << 8) | (b2 << 16) | (b3 << 24);
  }
  const int nt = n >> 4;
  const int c  = n & 15;
  signed char* base = WTf + (size_t)nt * (KD * 16) + c * 16;
#pragma unroll
  for (int j = 0; j < 4; ++j) {
    u32x4 o;
    o.x = buf[4 * j + 0];
    o.y = buf[4 * j + 1];
    o.z = buf[4 * j + 2];
    o.w = buf[4 * j + 3];
    *(u32x4*)(base + (size_t)(k0 / 16 + j) * 256) = o;
  }
}

// ---- 256x128 i8 GEMM, A-only LDS, B fragment-direct -----------------------

#define GLL16(g, l)                                                  \
  __builtin_amdgcn_global_load_lds(                                  \
      (const __attribute__((address_space(1))) void*)(g),            \
      (__attribute__((address_space(3))) void*)(l), 16, 0, 0)

#define BARRIER()    __builtin_amdgcn_s_barrier()
#define WAITL(N)     asm volatile("s_waitcnt lgkmcnt(" #N ")")
#define WAITV(N)     asm volatile("s_waitcnt vmcnt(" #N ")")
#define SCHED()      __builtin_amdgcn_sched_barrier(0)
#define PRIO1()      __builtin_amdgcn_s_setprio(1)
#define PRIO0()      __builtin_amdgcn_s_setprio(0)

__global__ __launch_bounds__(512, 4) void gemm_kernel(
    const signed char* __restrict__ Aq8,  // int8 [M][K]
    const signed char* __restrict__ Bf,   // int8 frag-linear [N/16][K/16][16][16]
    const float* __restrict__ xs,         // [M] row scales
    const float* __restrict__ scale,      // [N]
    float* __restrict__ C) {              // f32 [M][N]
  __shared__ __align__(16) char Asm[2][16384];

  const int tid  = threadIdx.x;
  const int lane = tid & 63;
  const int w    = tid >> 6;   // wave 0..7
  const int wm   = w >> 1;     // 0..3 : A rows wm*64..+63
  const int wn   = w & 1;      // 0..1 : B cols wn*64..+63

  // XCD supertile
  const int bid = blockIdx.x;            // 4096 = 8 chunks x 512
  const int xcd = bid & 7;
  const int pos = bid >> 3;
  const int tm  = (xcd << 2) | (pos & 3);   // 0..31
  const int tn  = pos >> 2;                 // 0..127
  const size_t brow = (size_t)tm * 256;
  const size_t bcol = (size_t)tn * 128;

  // A staging (pre-swizzled granule)
  const int srow  = tid >> 2;
  const int sgran = (tid & 3) ^ ((tid >> 3) & 3);
  const signed char* Ag = Aq8 + (brow + srow) * (size_t)KD + sgran * 16;

  // A fragment reads (LDS)
  const int r15  = lane & 15;
  const int kcsw = (((lane >> 4) ^ ((r15 >> 1) & 3)) << 4);

  // B fragment loads (global, frag-linear)
  const signed char* Bw = Bf + (size_t)(tn * 8 + wn * 4) * (KD * 16);
  const int bvoff = ((lane >> 4) << 8) + (r15 << 4);

  i32x4 acc[4][4];
#pragma unroll
  for (int i = 0; i < 4; ++i)
#pragma unroll
    for (int j = 0; j < 4; ++j) acc[i][j] = (i32x4){0, 0, 0, 0};

  i32x4 a[4], b[4];

  // ---- prologue: queue order [b01(0), GLLA(0), GLLA(1), b23(0)] ----
  b[0] = *(const i32x4*)(Bw + 0 * 65536 + bvoff);
  b[1] = *(const i32x4*)(Bw + 1 * 65536 + bvoff);
  SCHED();
  GLL16(Ag,                    &Asm[0][0] + w * 1024);
  GLL16(Ag + (size_t)128 * KD, &Asm[0][8192] + w * 1024);
  SCHED();
  GLL16(Ag + 64,                    &Asm[1][0] + w * 1024);
  GLL16(Ag + (size_t)128 * KD + 64, &Asm[1][8192] + w * 1024);
  SCHED();
  b[2] = *(const i32x4*)(Bw + 2 * 65536 + bvoff);
  b[3] = *(const i32x4*)(Bw + 3 * 65536 + bvoff);
  SCHED();
  WAITV(4);   // drains b01(0) + GLLA(0); leaves [GLLA(1):2, b23(0):2]
  SCHED();
  BARRIER();
  SCHED();
  {  // prime a(0) from buf0
    const char* Ab = &Asm[0][0] + (wm * 64 + r15) * 64 + kcsw;
#pragma unroll
    for (int mi = 0; mi < 4; ++mi) a[mi] = *(const i32x4*)(Ab + mi * 1024);
  }
  SCHED();

  // ---- main loop: 64 K-tiles ----
  // top invariant (steady): queue = [b01(t):2, GLLA(t+1):2, b23(t):2]
  // (iter 0: [GLLA(1):2, b23(0):2] with b01(0) already resident)
#pragma unroll 2
  for (int it = 0; it < NT; ++it) {
    const int h = it & 1;
    const char* AbN = &Asm[h ^ 1][0] + (wm * 64 + r15) * 64 + kcsw;
    const size_t kb2  = (size_t)((it + 2) & (NT - 1)) * 64;    // A stage
    const size_t kcb1 = (size_t)((it + 1) & (NT - 1)) * 1024;  // B frag

    WAITL(0);   // a(t) resident (prefetched under last iter's C2b / smeared)
    SCHED();
    WAITV(4);   // drain b01(t)
    SCHED();
    PRIO1();
#pragma unroll
    for (int mi = 0; mi < 4; ++mi)        // C1: 8 MFMA (ni 0,1)
#pragma unroll
      for (int ni = 0; ni < 2; ++ni)
        acc[mi][ni] = __builtin_amdgcn_mfma_i32_16x16x64_i8(
            a[mi], b[ni], acc[mi][ni], 0, 0, 0);
    PRIO0();
    SCHED();
    b[0] = *(const i32x4*)(Bw + 0 * 65536 + kcb1 + bvoff);  // b01(t+1)
    b[1] = *(const i32x4*)(Bw + 1 * 65536 + kcb1 + bvoff);
    SCHED();
    WAITV(2);   // drain GLLA(t+1) + b23(t) (both ~1 tile old)
    SCHED();
    // single barrier: (i) all waves past WAITL(0) -> buf[h] fully read;
    // (ii) all waves past WAITV(2) -> buf[h^1] fully staged with A(t+1).
    BARRIER();
    SCHED();
    PRIO1();
#pragma unroll
    for (int mi = 0; mi < 2; ++mi)        // C2a: 4 MFMA (mi 0,1 x ni 2,3)
#pragma unroll
      for (int ni = 2; ni < 4; ++ni)
        acc[mi][ni] = __builtin_amdgcn_mfma_i32_16x16x64_i8(
            a[mi], b[ni], acc[mi][ni], 0, 0, 0);
    PRIO0();
    SCHED();
    a[0] = *(const i32x4*)(AbN + 0 * 1024);   // pf a01(t+1)
    a[1] = *(const i32x4*)(AbN + 1 * 1024);
    SCHED();
    PRIO1();
#pragma unroll
    for (int mi = 2; mi < 4; ++mi)        // C2b: 4 MFMA (mi 2,3 x ni 2,3)
#pragma unroll
      for (int ni = 2; ni < 4; ++ni)      // covers pf a01 drain
        acc[mi][ni] = __builtin_amdgcn_mfma_i32_16x16x64_i8(
            a[mi], b[ni], acc[mi][ni], 0, 0, 0);
    PRIO0();
    SCHED();
    a[2] = *(const i32x4*)(AbN + 2 * 1024);   // pf a23(t+1) (smears to top)
    a[3] = *(const i32x4*)(AbN + 3 * 1024);
    SCHED();
    GLL16(Ag + kb2,                    &Asm[h][0] + w * 1024);   // A(t+2)
    GLL16(Ag + (size_t)128 * KD + kb2, &Asm[h][8192] + w * 1024);
    SCHED();
    b[2] = *(const i32x4*)(Bw + 2 * 65536 + kcb1 + bvoff);  // b23(t+1)
    b[3] = *(const i32x4*)(Bw + 3 * 65536 + kcb1 + bvoff);
    SCHED();
    // bottom queue: [b01(t+1):2, GLLA(t+2):2, b23(t+1):2] == top invariant
  }

  // ---- epilogue: float(acc) * xs[row] * (1/scale[col]) -> C ----
  const int r4 = (lane >> 4) << 2;
  float sxv[4][4];
#pragma unroll
  for (int mi = 0; mi < 4; ++mi)
#pragma unroll
    for (int r = 0; r < 4; ++r)
      sxv[mi][r] = xs[brow + wm * 64 + mi * 16 + r4 + r];
#pragma unroll
  for (int ni = 0; ni < 4; ++ni) {
    const size_t col = bcol + wn * 64 + ni * 16 + r15;
    const float inv = 1.0f / scale[col];
#pragma unroll
    for (int mi = 0; mi < 4; ++mi) {
      float* cp = C + (brow + wm * 64 + mi * 16 + r4) * (size_t)ND + col;
#pragma unroll
      for (int r = 0; r < 4; ++r)
        cp[(size_t)r * ND] = (float)acc[mi][ni][r] * sxv[mi][r] * inv;
    }
  }
}

}  // namespace

extern "C" void kernel_launch(void* const* d_in, const int* in_sizes, int n_in,
                              void* d_out, int out_size, void* d_ws,
                              size_t ws_size, hipStream_t stream) {
  const float* x     = (const float*)d_in[0];
  const int*   W     = (const int*)d_in[1];
  const float* scale = (const float*)d_in[2];
  float*       out   = (float*)d_out;

  signed char* xq = (signed char*)d_ws;                                  // 32 MB
  signed char* wf = (signed char*)d_ws + (size_t)32 * 1024 * 1024;       // 64 MB
  float*       xs = (float*)((char*)d_ws + (size_t)96 * 1024 * 1024);    // 32 KB

  quant_x_kernel<<<8192, 256, 0, stream>>>(x, xq, xs);
  transpose_w_kernel<<<4096, 256, 0, stream>>>(W, wf);
  gemm_kernel<<<4096, 512, 0, stream>>>(xq, wf, xs, scale, out);
}

// Round 13
// 747.964 us; speedup vs baseline: 1.0556x; 1.0556x over previous
//
#include <hip/hip_runtime.h>

// ---------------------------------------------------------------------------
// out[b,t,f] = sum_d x[b,t,d] * (W[d,f] / scale[f])
// GEMM: M=8192 (B*T), K=4096 (D), N=16384 (F)
// Round 13: R10 data path (A and B via LDS, granule swizzle, i8 16x16x64,
// 256x128 block, 64x64 wave, 2 blocks/CU) + cross-phase covered waits:
// a-prefetch and b01 are issued a half-tile before their wait, with MFMA
// clusters covering every drain. One barrier/tile.
// ws: [0,32M) xq int8 ; [32M,96M) WT int8 ; [96M,+32K) xs f32.
// ---------------------------------------------------------------------------

namespace {

constexpr int MD = 8192;    // B*T
constexpr int ND = 16384;   // F
constexpr int KD = 4096;    // D
constexpr int NT = KD / 64; // 64 k-tiles of BK=64

typedef float fl4 __attribute__((ext_vector_type(4)));
typedef unsigned int u32x4 __attribute__((ext_vector_type(4)));
typedef int i32x4 __attribute__((ext_vector_type(4)));

__device__ __forceinline__ unsigned int pack4(fl4 v, float sc) {
  int q0 = __float2int_rn(v.x * sc);
  int q1 = __float2int_rn(v.y * sc);
  int q2 = __float2int_rn(v.z * sc);
  int q3 = __float2int_rn(v.w * sc);
  return (q0 & 0xFF) | ((q1 & 0xFF) << 8) | ((q2 & 0xFF) << 16) |
         ((q3 & 0xFF) << 24);
}

// ---- x fp32 [M][K] -> int8 [M][K] + per-row scale -------------------------
__global__ __launch_bounds__(256) void quant_x_kernel(
    const float* __restrict__ x, signed char* __restrict__ xq,
    float* __restrict__ xs) {
  const int row = blockIdx.x;
  const int t   = threadIdx.x;
  const float* xr = x + (size_t)row * KD + t * 16;
  fl4 v0 = *(const fl4*)(xr);
  fl4 v1 = *(const fl4*)(xr + 4);
  fl4 v2 = *(const fl4*)(xr + 8);
  fl4 v3 = *(const fl4*)(xr + 12);
  float m = 0.f;
  m = fmaxf(m, fmaxf(fmaxf(fabsf(v0.x), fabsf(v0.y)), fmaxf(fabsf(v0.z), fabsf(v0.w))));
  m = fmaxf(m, fmaxf(fmaxf(fabsf(v1.x), fabsf(v1.y)), fmaxf(fabsf(v1.z), fabsf(v1.w))));
  m = fmaxf(m, fmaxf(fmaxf(fabsf(v2.x), fabsf(v2.y)), fmaxf(fabsf(v2.z), fabsf(v2.w))));
  m = fmaxf(m, fmaxf(fmaxf(fabsf(v3.x), fabsf(v3.y)), fmaxf(fabsf(v3.z), fabsf(v3.w))));
#pragma unroll
  for (int off = 32; off; off >>= 1) m = fmaxf(m, __shfl_xor(m, off));
  __shared__ float red[4];
  if ((t & 63) == 0) red[t >> 6] = m;
  __syncthreads();
  m = fmaxf(fmaxf(red[0], red[1]), fmaxf(red[2], red[3]));
  const float sc = (m > 0.f) ? 127.0f / m : 0.f;
  if (t == 0) xs[row] = (m > 0.f) ? m / 127.0f : 0.f;
  u32x4 o;
  o.x = pack4(v0, sc);
  o.y = pack4(v1, sc);
  o.z = pack4(v2, sc);
  o.w = pack4(v3, sc);
  *(u32x4*)(xq + (size_t)row * KD + t * 16) = o;
}

// ---- W int32 [K][N] -> int8 W^T [N][K] ------------------------------------
__global__ __launch_bounds__(256) void transpose_w_kernel(
    const int* __restrict__ W, signed char* __restrict__ WT) {
  constexpr int KC = 64;
  const int nb = blockIdx.x & 63;
  const int kb = blockIdx.x >> 6;
  const int n  = nb * 256 + threadIdx.x;
  const int k0 = kb * KC;
  const int* src = W + (size_t)k0 * ND + n;
  unsigned int buf[16];
#pragma unroll
  for (int i = 0; i < KC; i += 4) {
    unsigned int b0 = (unsigned)src[(size_t)(i + 0) * ND] & 0xFF;
    unsigned int b1 = (unsigned)src[(size_t)(i + 1) * ND] & 0xFF;
    unsigned int b2 = (unsigned)src[(size_t)(i + 2) * ND] & 0xFF;
    unsigned int b3 = (unsigned)src[(size_t)(i + 3) * ND] & 0xFF;
    buf[i >> 2] = b0 | (b1 << 8) | (b2 << 16) | (b3 << 24);
  }
  u32x4* dst = (u32x4*)(WT + (size_t)n * KD + k0);
#pragma unroll
  for (int j = 0; j < 4; ++j) {
    u32x4 o;
    o.x = buf[4 * j + 0];
    o.y = buf[4 * j + 1];
    o.z = buf[4 * j + 2];
    o.w = buf[4 * j + 3];
    dst[j] = o;
  }
}

// ---- 256x128 i8 GEMM, 2 blocks/CU, covered waits --------------------------

#define GLL16(g, l)                                                  \
  __builtin_amdgcn_global_load_lds(                                  \
      (const __attribute__((address_space(1))) void*)(g),            \
      (__attribute__((address_space(3))) void*)(l), 16, 0, 0)

#define BARRIER()    __builtin_amdgcn_s_barrier()
#define WAITL(N)     asm volatile("s_waitcnt lgkmcnt(" #N ")")
#define WAITV(N)     asm volatile("s_waitcnt vmcnt(" #N ")")
#define SCHED()      __builtin_amdgcn_sched_barrier(0)
#define PRIO1()      __builtin_amdgcn_s_setprio(1)
#define PRIO0()      __builtin_amdgcn_s_setprio(0)

__global__ __launch_bounds__(512, 4) void gemm_kernel(
    const signed char* __restrict__ Aq8,  // int8 [M][K]
    const signed char* __restrict__ Bq8,  // int8 [N][K] (W^T)
    const float* __restrict__ xs,         // [M] row scales
    const float* __restrict__ scale,      // [N]
    float* __restrict__ C) {              // f32 [M][N]
  // A tile 256x64 (16KB), B tile 128x64 (8KB), double-buffered: 48KB.
  __shared__ __align__(16) char Asm[2][16384];
  __shared__ __align__(16) char Bsm[2][8192];

  const int tid  = threadIdx.x;
  const int lane = tid & 63;
  const int w    = tid >> 6;   // wave 0..7
  const int wm   = w >> 1;     // 0..3 : A rows wm*64..+63
  const int wn   = w & 1;      // 0..1 : B cols wn*64..+63

  // XCD supertile: xcd owns tm in [4c,4c+4), sweeps tn 0..127 tm-fastest.
  const int bid = blockIdx.x;            // 4096 = 8 chunks x 512
  const int xcd = bid & 7;
  const int pos = bid >> 3;
  const int tm  = (xcd << 2) | (pos & 3);   // 0..31
  const int tn  = pos >> 2;                 // 0..127
  const size_t brow = (size_t)tm * 256;
  const size_t bcol = (size_t)tn * 128;

  // staging (pre-swizzled granule, rule #21)
  const int srow  = tid >> 2;
  const int sgran = (tid & 3) ^ ((tid >> 3) & 3);
  const signed char* Ag = Aq8 + (brow + srow) * (size_t)KD + sgran * 16;
  const signed char* Bg = Bq8 + (bcol + srow) * (size_t)KD + sgran * 16;

  // fragment reads: row = base + r15, swizzled k-granule
  const int r15  = lane & 15;
  const int kcsw = (((lane >> 4) ^ ((r15 >> 1) & 3)) << 4);

  i32x4 acc[4][4];
#pragma unroll
  for (int i = 0; i < 4; ++i)
#pragma unroll
    for (int j = 0; j < 4; ++j) acc[i][j] = (i32x4){0, 0, 0, 0};

  // ---- prologue: tiles 0 (buf0) and 1 (buf1), 3 GLL each ----
  GLL16(Ag,                         &Asm[0][0] + w * 1024);
  GLL16(Ag + (size_t)128 * KD,      &Asm[0][8192] + w * 1024);
  GLL16(Bg,                         &Bsm[0][0] + w * 1024);
  GLL16(Ag + 64,                    &Asm[1][0] + w * 1024);
  GLL16(Ag + (size_t)128 * KD + 64, &Asm[1][8192] + w * 1024);
  GLL16(Bg + 64,                    &Bsm[1][0] + w * 1024);
  SCHED();
  WAITV(3);   // tile0 resident; tile1's 3 loads in flight
  SCHED();
  BARRIER();
  SCHED();

  i32x4 a[4], b[4];
  // prime to match steady top invariant: ds queue = [a23(0), a01(0), b01(0)]
  {
    const char* Ab = &Asm[0][0] + (wm * 64 + r15) * 64 + kcsw;
    const char* Bb = &Bsm[0][0] + (wn * 64 + r15) * 64 + kcsw;
    a[2] = *(const i32x4*)(Ab + 2 * 1024);
    a[3] = *(const i32x4*)(Ab + 3 * 1024);
    SCHED();
    a[0] = *(const i32x4*)(Ab + 0 * 1024);
    a[1] = *(const i32x4*)(Ab + 1 * 1024);
    SCHED();
    b[0] = *(const i32x4*)(Bb + 0 * 1024);
    b[1] = *(const i32x4*)(Bb + 1 * 1024);
  }
  SCHED();

  // ---- main loop: 64 K-tiles, 1 barrier each ----
  // top invariant: ds = [a(t)x4, b01(t)x2] ; vm = [GLL(t+1)x3]
#pragma unroll 2
  for (int it = 0; it < NT; ++it) {
    const int h = it & 1;
    const char* Bb  = &Bsm[h][0] + (wn * 64 + r15) * 64 + kcsw;
    const char* AbN = &Asm[h ^ 1][0] + (wm * 64 + r15) * 64 + kcsw;
    const char* BbN = &Bsm[h ^ 1][0] + (wn * 64 + r15) * 64 + kcsw;
    const size_t kb2 = (size_t)((it + 2) & (NT - 1)) * 64;

    // issue b23(t); everything older is >= half a tile old
    b[2] = *(const i32x4*)(Bb + 2 * 1024);
    b[3] = *(const i32x4*)(Bb + 3 * 1024);
    SCHED();
    WAITL(2);   // drain a(t)x4 + b01(t) (all covered); b23 in flight
    SCHED();
    PRIO1();
#pragma unroll
    for (int mi = 0; mi < 4; ++mi)        // C1: 8 MFMA (ni 0,1) cover b23
#pragma unroll
      for (int ni = 0; ni < 2; ++ni)
        acc[mi][ni] = __builtin_amdgcn_mfma_i32_16x16x64_i8(
            a[mi], b[ni], acc[mi][ni], 0, 0, 0);
    PRIO0();
    SCHED();
    WAITL(0);   // b23 resident (covered by C1)
    SCHED();
    PRIO1();
#pragma unroll
    for (int mi = 2; mi < 4; ++mi)        // C2a: 4 MFMA (mi 2,3 x ni 2,3)
#pragma unroll
      for (int ni = 2; ni < 4; ++ni)      // frees a23
        acc[mi][ni] = __builtin_amdgcn_mfma_i32_16x16x64_i8(
            a[mi], b[ni], acc[mi][ni], 0, 0, 0);
    PRIO0();
    SCHED();
    WAITV(0);   // GLL(t+1) resident (issued a full tile ago)
    SCHED();
    // single barrier: buf[h] fully read (WAITL(0)) + buf[h^1] fully staged
    BARRIER();
    SCHED();
    a[2] = *(const i32x4*)(AbN + 2 * 1024);   // apf a23(t+1)
    a[3] = *(const i32x4*)(AbN + 3 * 1024);
    SCHED();
    PRIO1();
#pragma unroll
    for (int mi = 0; mi < 2; ++mi)        // C2b: 4 MFMA (mi 0,1 x ni 2,3)
#pragma unroll
      for (int ni = 2; ni < 4; ++ni)      // covers a23' drain; frees a01,b
        acc[mi][ni] = __builtin_amdgcn_mfma_i32_16x16x64_i8(
            a[mi], b[ni], acc[mi][ni], 0, 0, 0);
    PRIO0();
    SCHED();
    a[0] = *(const i32x4*)(AbN + 0 * 1024);   // apf a01(t+1)
    a[1] = *(const i32x4*)(AbN + 1 * 1024);
    SCHED();
    b[0] = *(const i32x4*)(BbN + 0 * 1024);   // b01(t+1) from staged buf
    b[1] = *(const i32x4*)(BbN + 1 * 1024);
    SCHED();
    GLL16(Ag + kb2,                    &Asm[h][0] + w * 1024);   // tile t+2
    GLL16(Ag + (size_t)128 * KD + kb2, &Asm[h][8192] + w * 1024);
    GLL16(Bg + kb2,                    &Bsm[h][0] + w * 1024);
    SCHED();
    // end: ds = [a23',a01',b01'] ; vm = [GLL(t+2)x3] == top invariant
  }

  // ---- epilogue: float(acc) * xs[row] * (1/scale[col]) -> C ----
  const int r4 = (lane >> 4) << 2;
  float sxv[4][4];
#pragma unroll
  for (int mi = 0; mi < 4; ++mi)
#pragma unroll
    for (int r = 0; r < 4; ++r)
      sxv[mi][r] = xs[brow + wm * 64 + mi * 16 + r4 + r];
#pragma unroll
  for (int ni = 0; ni < 4; ++ni) {
    const size_t col = bcol + wn * 64 + ni * 16 + r15;
    const float inv = 1.0f / scale[col];
#pragma unroll
    for (int mi = 0; mi < 4; ++mi) {
      float* cp = C + (brow + wm * 64 + mi * 16 + r4) * (size_t)ND + col;
#pragma unroll
      for (int r = 0; r < 4; ++r)
        cp[(size_t)r * ND] = (float)acc[mi][ni][r] * sxv[mi][r] * inv;
    }
  }
}

}  // namespace

extern "C" void kernel_launch(void* const* d_in, const int* in_sizes, int n_in,
                              void* d_out, int out_size, void* d_ws,
                              size_t ws_size, hipStream_t stream) {
  const float* x     = (const float*)d_in[0];
  const int*   W     = (const int*)d_in[1];
  const float* scale = (const float*)d_in[2];
  float*       out   = (float*)d_out;

  signed char* xq = (signed char*)d_ws;                                  // 32 MB
  signed char* wq = (signed char*)d_ws + (size_t)32 * 1024 * 1024;       // 64 MB
  float*       xs = (float*)((char*)d_ws + (size_t)96 * 1024 * 1024);    // 32 KB

  quant_x_kernel<<<8192, 256, 0, stream>>>(x, xq, xs);
  transpose_w_kernel<<<4096, 256, 0, stream>>>(W, wq);
  gemm_kernel<<<4096, 512, 0, stream>>>(xq, wq, xs, scale, out);
}